// Round 1
// baseline (73.544 us; speedup 1.0000x reference)
//
#include <hip/hip_runtime.h>

// Problem constants (from reference)
#define NB   2
#define CC   10
#define HH   30
#define WW   30
#define PADR 4
#define DD   11           // C+1
#define NPIX (NB*HH*WW)   // 1800 pixels

// ---------------- Fused kernel: one WAVE (64 thr) per pixel -----------------
// seq rows are one-hot -> per-channel softmax-attention reduces to a class-
// histogram weighted sum; only the indicator-query (class 10) row is ever
// needed (validated bit-exact in the previous session, R4-R7).
//
// Restructure vs previous version: single wave per block, no idle waves, no
// cross-wave barriers. Weight rows + exp tables live in per-lane REGISTERS
// (issued at kernel top; latency hides under the window-decode loads). All 64
// lanes run the 11-dim pipeline as 4 redundant 16-lane groups. LayerNorms use
// merged moments (sum & sumsq in ONE 4-stage shfl chain); channel softmax
// drops max-subtraction (|hc| <= ~3.3 post-LN, exp is safe).
__global__ __launch_bounds__(64) void pve_fused(
    const float* __restrict__ x,      // (N,C,H,W) one-hot
    const float* __restrict__ w_in,   // (33,11)
    const float* __restrict__ w_out,  // (11,11)
    const float* __restrict__ w_ff1,  // (1,11)
    const float* __restrict__ w_ff2,  // (11,1)
    const float* __restrict__ ln1g,   // (11,)
    const float* __restrict__ ln2g,   // (11,)
    float* __restrict__ out)          // (1800,10,100) f32
{
    __shared__ float cntf[11];
    volatile __shared__ float aoS[16];  // in-wave DS broadcast (in-order pipe)
    __shared__ float smvS[10];
    __shared__ unsigned char chs[100];  // slot classes (255 = invalid)

    const int t   = threadIdx.x;        // 0..63
    const int pix = blockIdx.x;
    const int n   = pix / (HH * WW);
    const int rm  = pix % (HH * WW);
    const int i0  = rm / WW, j0 = rm % WW;

    const int g = t & 15;               // 4 redundant 16-lane groups
    const int d = (g < 11) ? g : 0;

    // ---- phase 0: prefetch weight rows into registers (loads issue now,
    //      complete while the decode loads are classified) ----
    const float Q  = w_in[d * DD + 10];
    float Krow[11], Vrow[11], Wrow[11];
    #pragma unroll
    for (int c = 0; c < 11; c++) {
        Krow[c] = w_in[(DD + d) * DD + c];
        Vrow[c] = w_in[(2 * DD + d) * DD + c];
        Wrow[c] = w_out[d * DD + c];
    }
    const float g1 = ln1g[d], g2 = ln2g[d];
    const float f1 = w_ff1[d], f2 = w_ff2[d];

    // ---- phase A: window decode + byte-packed histogram (no atomics) ----
    unsigned int pk0 = 0, pk1 = 0, pk2 = 0;  // classes 0-3 / 4-7 / 8-10
    #pragma unroll
    for (int it = 0; it < 2; ++it) {
        const int l = t + it * 64;
        if (l < 100) {
            const int ph = l / 10, pw = l % 10;
            unsigned int c = 255;            // invalid slot (ph>=9 || pw>=9)
            if (ph < 9 && pw < 9) {
                const int r  = i0 + ph - PADR;
                const int cc = j0 + pw - PADR;
                c = 10;                      // border indicator
                if (r >= 0 && r < HH && cc >= 0 && cc < WW) {
                    // branch-free one-hot decode: 10 independent L2-hit loads
                    const float* xp = x + n * CC * HH * WW + r * WW + cc;
                    int cls = 10;
                    #pragma unroll
                    for (int k = CC - 1; k >= 0; k--) {
                        if (xp[k * HH * WW] > 0.5f) cls = k;
                    }
                    c = (unsigned int)cls;
                }
                const unsigned int inc = 1u << ((c & 3) * 8);
                if (c < 4) pk0 += inc; else if (c < 8) pk1 += inc; else pk2 += inc;
            }
            chs[l] = (unsigned char)c;
        }
    }

    // ---- phase B: exp tables in registers (independent of phase A) ----
    float ec[11], ev[11];
    #pragma unroll
    for (int c = 0; c < 11; c++) {
        const float e = __expf(Q * Krow[c]);
        ec[c] = e;
        ev[c] = e * Vrow[c];
    }

    // ---- phase C: 6-stage xor reduce across the wave (counts fit a byte) ----
    #pragma unroll
    for (int m = 1; m < 64; m <<= 1) {
        pk0 += __shfl_xor(pk0, m, 64);
        pk1 += __shfl_xor(pk1, m, 64);
        pk2 += __shfl_xor(pk2, m, 64);
    }
    if (t < 11) {
        const unsigned int pk = (t < 4) ? pk0 : ((t < 8) ? pk1 : pk2);
        cntf[t] = (float)((pk >> ((t & 3) * 8)) & 0xFFu);
    }
    __syncthreads();   // single-wave block: lgkmcnt drain + compiler fence

    // ---- phase D: 11-dim pipeline, all 64 lanes (wave-synchronous) ----
    {
        // attention via histogram: ao[d] = sum(cnt*ec)/sum(cnt*e)
        float s1 = 0.f, s2 = 0.f;
        #pragma unroll
        for (int c = 0; c < 11; c++) {
            const float cn = cntf[c];
            s1 += cn * ec[c];
            s2 += cn * ev[c];
        }
        const float ao = s2 / s1;

        // broadcast ao via LDS (in-order DS pipe within a wave; volatile
        // stops compiler reordering); w_out matvec from registers
        aoS[g] = ao;
        float h = 0.f;
        #pragma unroll
        for (int j = 0; j < 11; j++)
            h += Wrow[j] * aoS[j];
        if (g == 10) h += 1.0f;          // residual: indicator one-hot
        if (g >= 11) h = 0.f;

        // LN1 — merged moments: one 4-stage reduce carries sum AND sumsq
        float s = h, sq = h * h;
        #pragma unroll
        for (int m = 1; m < 16; m <<= 1) {
            s  += __shfl_xor(s,  m, 16);
            sq += __shfl_xor(sq, m, 16);
        }
        const float mean1 = s * (1.f / 11.f);
        const float var1  = sq * (1.f / 11.f) - mean1 * mean1;
        float dv = (g < 11) ? (h - mean1) : 0.f;
        const float hb = dv * rsqrtf(var1 + 1e-5f) * g1;

        // FF (scalar bottleneck) + residual
        float f = hb * f1;
        #pragma unroll
        for (int m = 1; m < 16; m <<= 1) f += __shfl_xor(f, m, 16);
        f = fmaxf(f, 0.f);
        float h2 = hb + f * f2;
        if (g >= 11) h2 = 0.f;

        // LN2 — merged moments
        s = h2; sq = h2 * h2;
        #pragma unroll
        for (int m = 1; m < 16; m <<= 1) {
            s  += __shfl_xor(s,  m, 16);
            sq += __shfl_xor(sq, m, 16);
        }
        const float mean2 = s * (1.f / 11.f);
        const float var2  = sq * (1.f / 11.f) - mean2 * mean2;
        dv = (g < 11) ? (h2 - mean2) : 0.f;
        const float hc = dv * rsqrtf(var2 + 1e-5f) * g2;

        // softmax over channels 0..9 — no max-subtraction (|hc| <= ~3.3)
        const float ex = (g < 10) ? __expf(hc) : 0.f;
        float den = ex;
        #pragma unroll
        for (int m = 1; m < 16; m <<= 1) den += __shfl_xor(den, m, 16);
        if (t < 10) smvS[t] = ex / den;  // group 0 writes
    }
    __syncthreads();

    // ---- phase E: epilogue, 250 float4 stores, 4 per lane --------------
    // out[pix, c, l]: invalid -> 0; class cl<10 -> one-hot; cl==10 -> smv[c].
    // float4 never crosses a c boundary (4 | 100); l0+3 <= 99 stays in chs.
    #pragma unroll
    for (int it = 0; it < 4; ++it) {
        const int q = t + it * 64;       // float4 index 0..249
        if (q < 250) {
            const int c  = q / 25;       // 0..9, constant within float4
            const int l0 = (q - c * 25) * 4;
            const uchar4 c4 = *reinterpret_cast<const uchar4*>(chs + l0);
            const float sv = smvS[c];
            float4 v4;
            v4.x = (c4.x == 255) ? 0.f : ((c4.x < 10) ? ((c == c4.x) ? 1.f : 0.f) : sv);
            v4.y = (c4.y == 255) ? 0.f : ((c4.y < 10) ? ((c == c4.y) ? 1.f : 0.f) : sv);
            v4.z = (c4.z == 255) ? 0.f : ((c4.z < 10) ? ((c == c4.z) ? 1.f : 0.f) : sv);
            v4.w = (c4.w == 255) ? 0.f : ((c4.w < 10) ? ((c == c4.w) ? 1.f : 0.f) : sv);
            reinterpret_cast<float4*>(out + (size_t)pix * 1000)[q] = v4;
        }
    }
}

extern "C" void kernel_launch(void* const* d_in, const int* in_sizes, int n_in,
                              void* d_out, int out_size, void* d_ws, size_t ws_size,
                              hipStream_t stream) {
    const float* x     = (const float*)d_in[0];
    const float* w_in  = (const float*)d_in[1];
    const float* w_out = (const float*)d_in[2];
    const float* w_ff1 = (const float*)d_in[3];
    const float* w_ff2 = (const float*)d_in[4];
    const float* ln1g  = (const float*)d_in[5];
    const float* ln2g  = (const float*)d_in[6];
    float* out = (float*)d_out;

    pve_fused<<<NPIX, 64, 0, stream>>>(x, w_in, w_out, w_ff1, w_ff2,
                                       ln1g, ln2g, out);
}